// Round 3
// baseline (403.959 us; speedup 1.0000x reference)
//
#include <hip/hip_runtime.h>

// Problem constants (match reference)
static constexpr int kB   = 256;      // batch
static constexpr int kD   = 128;      // proj dim
static constexpr int kN   = 1296;     // 36*36 pixels
static constexpr int kN4  = kN / 4;   // 324 float4 per row
static constexpr int kC   = 64;       // classes
static constexpr int kDC  = 32;       // d-rows per block
static constexpr int kNCH = kD / kDC; // 4 chunks
static constexpr float kEPS = 1e-4f;

// ---------------------------------------------------------------------------
// Fused kernel: one block per (d-chunk, image).
// Thread t owns float4 pixel-groups t and t+256 (t<68) of every d-row.
// Phases:
//   A) zero LDS sums/counts
//   B) load class ids (int4, registers) + LDS count atomics
//   C) sweep 32 x-rows (float4, coalesced, 2-deep prefetch)
//      -> per-class sums via LDS float atomics
//   D) sums -> means in place (divide by count+eps)
//   E) re-sweep the same rows (L3-resident), accumulate per-pixel squared
//      distance in registers, one global atomicAdd per pixel per chunk.
// ---------------------------------------------------------------------------
__global__ __launch_bounds__(256) void k_fused(const float* __restrict__ x,
                                               const int*   __restrict__ cm,
                                               float* __restrict__ out)   // [B][N]
{
    __shared__ float sums_s[kDC][kC];
    __shared__ int   cnt_s[kC];

    const int chunk = blockIdx.x;
    const int b     = blockIdx.y;
    const int tid   = threadIdx.x;
    const bool has1 = tid < (kN4 - 256);   // 68 threads own a second group

    // A) zero accumulators
    for (int i = tid; i < kDC * kC; i += 256) (&sums_s[0][0])[i] = 0.f;
    if (tid < kC) cnt_s[tid] = 0;
    __syncthreads();

    // B) class ids in registers + counts
    const int4* cm4 = (const int4*)(cm + (size_t)b * kN);
    const int4 c0 = cm4[tid];
    const int4 c1 = cm4[has1 ? (tid + 256) : 0];
    atomicAdd(&cnt_s[c0.x], 1);
    atomicAdd(&cnt_s[c0.y], 1);
    atomicAdd(&cnt_s[c0.z], 1);
    atomicAdd(&cnt_s[c0.w], 1);
    if (has1) {
        atomicAdd(&cnt_s[c1.x], 1);
        atomicAdd(&cnt_s[c1.y], 1);
        atomicAdd(&cnt_s[c1.z], 1);
        atomicAdd(&cnt_s[c1.w], 1);
    }

    // C) class sums, 2-deep prefetch across rows
    const float4* xp = (const float4*)(x + ((size_t)b * kD + (size_t)chunk * kDC) * kN);
    float4 v0 = xp[tid];
    float4 v1 = xp[has1 ? (tid + 256) : 0];
#pragma unroll 4
    for (int dd = 0; dd < kDC; ++dd) {
        const int ddn = (dd + 1 < kDC) ? (dd + 1) : (kDC - 1);
        const float4* xn = xp + (size_t)ddn * kN4;
        const float4 n0 = xn[tid];
        const float4 n1 = xn[has1 ? (tid + 256) : 0];

        atomicAdd(&sums_s[dd][c0.x], v0.x);
        atomicAdd(&sums_s[dd][c0.y], v0.y);
        atomicAdd(&sums_s[dd][c0.z], v0.z);
        atomicAdd(&sums_s[dd][c0.w], v0.w);
        if (has1) {
            atomicAdd(&sums_s[dd][c1.x], v1.x);
            atomicAdd(&sums_s[dd][c1.y], v1.y);
            atomicAdd(&sums_s[dd][c1.z], v1.z);
            atomicAdd(&sums_s[dd][c1.w], v1.w);
        }
        v0 = n0;
        v1 = n1;
    }
    __syncthreads();   // counts + sums complete

    // D) sums -> means in place
    for (int i = tid; i < kDC * kC; i += 256) {
        (&sums_s[0][0])[i] /= ((float)cnt_s[i & (kC - 1)] + kEPS);
    }
    __syncthreads();

    // E) distance sweep (rows now L3-resident)
    float acc0[4] = {0.f, 0.f, 0.f, 0.f};
    float acc1[4] = {0.f, 0.f, 0.f, 0.f};
#pragma unroll 2
    for (int dd = 0; dd < kDC; ++dd) {
        const float4* xr = xp + (size_t)dd * kN4;
        {
            const float4 v = xr[tid];
            const float d0 = v.x - sums_s[dd][c0.x];
            const float d1 = v.y - sums_s[dd][c0.y];
            const float d2 = v.z - sums_s[dd][c0.z];
            const float d3 = v.w - sums_s[dd][c0.w];
            acc0[0] += d0 * d0; acc0[1] += d1 * d1;
            acc0[2] += d2 * d2; acc0[3] += d3 * d3;
        }
        if (has1) {
            const float4 v = xr[tid + 256];
            const float d0 = v.x - sums_s[dd][c1.x];
            const float d1 = v.y - sums_s[dd][c1.y];
            const float d2 = v.z - sums_s[dd][c1.z];
            const float d3 = v.w - sums_s[dd][c1.w];
            acc1[0] += d0 * d0; acc1[1] += d1 * d1;
            acc1[2] += d2 * d2; acc1[3] += d3 * d3;
        }
    }

    const float inv = 1.0f / (float)kD;
    float* ob = out + (size_t)b * kN;
#pragma unroll
    for (int j = 0; j < 4; ++j) atomicAdd(&ob[4 * tid + j], acc0[j] * inv);
    if (has1) {
#pragma unroll
        for (int j = 0; j < 4; ++j)
            atomicAdd(&ob[4 * (tid + 256) + j], acc1[j] * inv);
    }
}

extern "C" void kernel_launch(void* const* d_in, const int* in_sizes, int n_in,
                              void* d_out, int out_size, void* d_ws, size_t ws_size,
                              hipStream_t stream) {
    const float* x   = (const float*)d_in[0];
    const int*   cm  = (const int*)d_in[1];
    float*       out = (float*)d_out;

    // Output is re-poisoned to 0xAA before every timed launch; zero it.
    hipMemsetAsync(d_out, 0, (size_t)out_size * sizeof(float), stream);

    dim3 grid(kNCH, kB);
    k_fused<<<grid, 256, 0, stream>>>(x, cm, out);
}

// Round 9
// 398.100 us; speedup vs baseline: 1.0147x; 1.0147x over previous
//
#include <hip/hip_runtime.h>

// Problem constants (match reference)
static constexpr int kB   = 256;      // batch
static constexpr int kD   = 128;      // proj dim
static constexpr int kN   = 1296;     // 36*36 pixels
static constexpr int kN4  = kN / 4;   // 324 float4 per row
static constexpr int kC   = 64;       // classes
static constexpr int kDC  = 16;       // d-rows per block (-> 2048 blocks, 8/CU)
static constexpr int kNCH = kD / kDC; // 8 chunks
static constexpr int kREP = 4;        // LDS sum replicas (quarter-wave keyed)
static constexpr float kEPS = 1e-4f;

// Native fp32 atomic. Plain atomicAdd on float compiles to a CAS loop without
// -munsafe-fp-atomics -> round-3 counters showed a latency-bound collapse
// (VALUBusy 2%, HBM 10%, dur 236us; native ds_add would cost ~1.5k cy/block).
// unsafeAtomicAdd lowers to ds_add_f32 on LDS pointers unconditionally.
__device__ __forceinline__ void fadd_lds(float* p, float v) { unsafeAtomicAdd(p, v); }

// ---------------------------------------------------------------------------
// Fused kernel: one block per (d-chunk, image).
// Thread t owns float4 pixel-groups t and t+256 (t<68) of every d-row.
//   A) zero LDS sums (4 replicas) / counts
//   B) class ids -> registers; LDS int count atomics
//   C) sweep 16 x-rows (float4, coalesced, 1-deep prefetch)
//      -> per-class sums via native LDS fp atomics, replica = quarter-wave
//   D) merge replicas, divide by count+eps -> means (into replica 0)
//   E) re-sweep the same rows (cache-resident), per-pixel squared distance
//      in registers, plain (non-atomic) partial store to workspace.
// ---------------------------------------------------------------------------
__global__ __launch_bounds__(256) void k_fused(const float* __restrict__ x,
                                               const int*   __restrict__ cm,
                                               float* __restrict__ part)  // [NCH][B][N]
{
    __shared__ float sums_s[kREP][kDC][kC];   // 16 KB
    __shared__ int   cnt_s[kC];

    const int chunk = blockIdx.x;
    const int b     = blockIdx.y;
    const int tid   = threadIdx.x;
    const int rep   = (tid >> 4) & (kREP - 1);   // 16 lanes per replica
    const bool has1 = tid < (kN4 - 256);         // 68 threads own a second group

    // A) zero accumulators
    for (int i = tid; i < kREP * kDC * kC; i += 256) (&sums_s[0][0][0])[i] = 0.f;
    if (tid < kC) cnt_s[tid] = 0;
    __syncthreads();

    // B) class ids in registers + counts (int atomics are native)
    const int4* cm4 = (const int4*)(cm + (size_t)b * kN);
    const int4 c0 = cm4[tid];
    const int4 c1 = cm4[has1 ? (tid + 256) : 0];
    atomicAdd(&cnt_s[c0.x], 1);
    atomicAdd(&cnt_s[c0.y], 1);
    atomicAdd(&cnt_s[c0.z], 1);
    atomicAdd(&cnt_s[c0.w], 1);
    if (has1) {
        atomicAdd(&cnt_s[c1.x], 1);
        atomicAdd(&cnt_s[c1.y], 1);
        atomicAdd(&cnt_s[c1.z], 1);
        atomicAdd(&cnt_s[c1.w], 1);
    }

    // C) class sums, 1-deep prefetch across rows
    const float4* xp = (const float4*)(x + ((size_t)b * kD + (size_t)chunk * kDC) * kN);
    float4 v0 = xp[tid];
    float4 v1 = xp[has1 ? (tid + 256) : 0];
    float* srow = &sums_s[rep][0][0];
#pragma unroll 4
    for (int dd = 0; dd < kDC; ++dd) {
        const int ddn = (dd + 1 < kDC) ? (dd + 1) : (kDC - 1);
        const float4* xn = xp + (size_t)ddn * kN4;
        const float4 n0 = xn[tid];
        const float4 n1 = xn[has1 ? (tid + 256) : 0];

        float* s = srow + dd * kC;
        fadd_lds(s + c0.x, v0.x);
        fadd_lds(s + c0.y, v0.y);
        fadd_lds(s + c0.z, v0.z);
        fadd_lds(s + c0.w, v0.w);
        if (has1) {
            fadd_lds(s + c1.x, v1.x);
            fadd_lds(s + c1.y, v1.y);
            fadd_lds(s + c1.z, v1.z);
            fadd_lds(s + c1.w, v1.w);
        }
        v0 = n0;
        v1 = n1;
    }
    __syncthreads();   // counts + sums complete

    // D) merge replicas, sums -> means (into replica 0)
    for (int i = tid; i < kDC * kC; i += 256) {
        float s = (&sums_s[0][0][0])[i];
#pragma unroll
        for (int r = 1; r < kREP; ++r) s += (&sums_s[r][0][0])[i];
        (&sums_s[0][0][0])[i] = s / ((float)cnt_s[i & (kC - 1)] + kEPS);
    }
    __syncthreads();

    // E) distance sweep (rows L2/L3-resident after phase C)
    float acc0[4] = {0.f, 0.f, 0.f, 0.f};
    float acc1[4] = {0.f, 0.f, 0.f, 0.f};
#pragma unroll 4
    for (int dd = 0; dd < kDC; ++dd) {
        const float4* xr = xp + (size_t)dd * kN4;
        const float* m = &sums_s[0][dd][0];
        {
            const float4 v = xr[tid];
            const float d0 = v.x - m[c0.x];
            const float d1 = v.y - m[c0.y];
            const float d2 = v.z - m[c0.z];
            const float d3 = v.w - m[c0.w];
            acc0[0] += d0 * d0; acc0[1] += d1 * d1;
            acc0[2] += d2 * d2; acc0[3] += d3 * d3;
        }
        if (has1) {
            const float4 v = xr[tid + 256];
            const float d0 = v.x - m[c1.x];
            const float d1 = v.y - m[c1.y];
            const float d2 = v.z - m[c1.z];
            const float d3 = v.w - m[c1.w];
            acc1[0] += d0 * d0; acc1[1] += d1 * d1;
            acc1[2] += d2 * d2; acc1[3] += d3 * d3;
        }
    }

    // Non-atomic partial store: part[chunk][b][n]
    float* pb = part + ((size_t)chunk * kB + b) * kN;
    {
        float4 o; o.x = acc0[0]; o.y = acc0[1]; o.z = acc0[2]; o.w = acc0[3];
        ((float4*)pb)[tid] = o;
    }
    if (has1) {
        float4 o; o.x = acc1[0]; o.y = acc1[1]; o.z = acc1[2]; o.w = acc1[3];
        ((float4*)pb)[tid + 256] = o;
    }
}

// ---------------------------------------------------------------------------
// Reduce: out[b][n] = (1/D) * sum_chunk part[chunk][b][n]. Contention-free.
// ---------------------------------------------------------------------------
__global__ __launch_bounds__(256) void k_reduce(const float* __restrict__ part,
                                                float* __restrict__ out)
{
    const size_t i = (size_t)blockIdx.x * 256 + threadIdx.x;   // float4 index
    const size_t n4_total = (size_t)kB * kN / 4;               // 82944
    if (i >= n4_total) return;

    float4 a = ((const float4*)part)[i];
#pragma unroll
    for (int c = 1; c < kNCH; ++c) {
        const float4 p = ((const float4*)part)[(size_t)c * n4_total + i];
        a.x += p.x; a.y += p.y; a.z += p.z; a.w += p.w;
    }
    const float inv = 1.0f / (float)kD;
    a.x *= inv; a.y *= inv; a.z *= inv; a.w *= inv;
    ((float4*)out)[i] = a;
}

extern "C" void kernel_launch(void* const* d_in, const int* in_sizes, int n_in,
                              void* d_out, int out_size, void* d_ws, size_t ws_size,
                              hipStream_t stream) {
    const float* x   = (const float*)d_in[0];
    const int*   cm  = (const int*)d_in[1];
    float*       out = (float*)d_out;
    float*       part = (float*)d_ws;    // kNCH * kB * kN floats = 10.6 MB

    dim3 grid(kNCH, kB);
    k_fused<<<grid, 256, 0, stream>>>(x, cm, part);

    const int n4_total = kB * kN / 4;    // 82944
    k_reduce<<<(n4_total + 255) / 256, 256, 0, stream>>>(part, out);
}

// Round 13
// 277.089 us; speedup vs baseline: 1.4579x; 1.4367x over previous
//
#include <hip/hip_runtime.h>

// Problem constants (match reference)
static constexpr int kB   = 256;      // batch
static constexpr int kD   = 128;      // proj dim
static constexpr int kN   = 1296;     // 36*36 pixels
static constexpr int kN4  = 324;      // float4 groups per row
static constexpr int kC   = 64;       // classes
static constexpr int kDC  = 8;        // d-rows per block -> x held in registers
static constexpr int kNCH = kD / kDC; // 16 chunks
static constexpr int kREP = 4;        // LDS sum replicas (quarter-wave keyed)
static constexpr int kT   = 384;      // 6 waves; lanes >= 324 idle in compute
static constexpr float kEPS = 1e-4f;
// Fixed-point scale for LDS int accumulation: 2^17.
// Worst case |sum| <= 1296 * 5sigma * 2^17 ~ 8.5e8 < 2^31. Quantization
// error ~4e-6/element, negligible vs observed absmax tolerance (~8e-3).
static constexpr float kSCALE     = 131072.0f;
static constexpr float kINV_SCALE = 1.0f / 131072.0f;

// Global fp32 atomic fan-in (16 chunks per pixel); native global_atomic_add.
__device__ __forceinline__ void fadd_glb(float* p, float v) { unsafeAtomicAdd(p, v); }

// ---------------------------------------------------------------------------
// Single-pass fused kernel: one block per (d-chunk, image).
// Thread t < 324 owns ONE float4 pixel-group of each of the 8 d-rows; all 8
// row-loads issued up front (no dependent load chain). x read from HBM once.
// Class-sum scatter uses INT fixed-point LDS atomics (ds_add_u32 — native in
// every lowering path, unlike fp32 LDS atomics whose generic-pointer lowering
// is the prime suspect for the invariant 230us / VALUBusy 2% / HBM 10%
// collapse in rounds 3 and 9: native ds_add_f32 arithmetic says ~16us, a CAS
// retry loop says ~200+us — only the latter matches the data).
// ---------------------------------------------------------------------------
__global__ __launch_bounds__(kT) void k_fused(const float* __restrict__ x,
                                              const int*   __restrict__ cm,
                                              float* __restrict__ out)   // [B][N]
{
    __shared__ int   isum_s[kREP][kDC][kC];   // 8 KB fixed-point sums
    __shared__ float means_s[kDC][kC];        // 2 KB
    __shared__ int   cnt_s[kC];

    const int chunk = blockIdx.x;
    const int b     = blockIdx.y;
    const int tid   = threadIdx.x;
    const int rep   = (tid >> 4) & (kREP - 1);   // quarter-wave keyed
    const int rot   = rep << 3;                  // bank-decorrelating rotation
    const bool act  = tid < kN4;

    // A) zero accumulators
    for (int i = tid; i < kREP * kDC * kC; i += kT) (&isum_s[0][0][0])[i] = 0;
    if (tid < kC) cnt_s[tid] = 0;
    __syncthreads();

    // B) class ids -> registers (coalesced int4)
    int4 c0 = make_int4(0, 0, 0, 0);
    if (act) c0 = ((const int4*)(cm + (size_t)b * kN))[tid];

    // C) all 8 row-loads issued up front, independent
    const float4* xp = (const float4*)(x + ((size_t)b * kD + (size_t)chunk * kDC) * kN);
    float4 va[kDC];
#pragma unroll
    for (int dd = 0; dd < kDC; ++dd)
        va[dd] = act ? xp[(size_t)dd * kN4 + tid] : make_float4(0.f, 0.f, 0.f, 0.f);

    if (act) {
        atomicAdd(&cnt_s[c0.x], 1);
        atomicAdd(&cnt_s[c0.y], 1);
        atomicAdd(&cnt_s[c0.z], 1);
        atomicAdd(&cnt_s[c0.w], 1);
        const int sx = (c0.x + rot) & (kC - 1);
        const int sy = (c0.y + rot) & (kC - 1);
        const int sz = (c0.z + rot) & (kC - 1);
        const int sw = (c0.w + rot) & (kC - 1);
#pragma unroll
        for (int dd = 0; dd < kDC; ++dd) {
            int* s = &isum_s[rep][dd][0];
            atomicAdd(s + sx, __float2int_rn(va[dd].x * kSCALE));
            atomicAdd(s + sy, __float2int_rn(va[dd].y * kSCALE));
            atomicAdd(s + sz, __float2int_rn(va[dd].z * kSCALE));
            atomicAdd(s + sw, __float2int_rn(va[dd].w * kSCALE));
        }
    }
    __syncthreads();

    // D) merge replicas (undo rotation), -> float means
    for (int i = tid; i < kDC * kC; i += kT) {
        const int dd = i >> 6;
        const int c  = i & (kC - 1);
        int s = isum_s[0][dd][c];                    // rot 0 = identity
#pragma unroll
        for (int r = 1; r < kREP; ++r)
            s += isum_s[r][dd][(c + (r << 3)) & (kC - 1)];
        means_s[dd][c] = (float)s * kINV_SCALE / ((float)cnt_s[c] + kEPS);
    }
    __syncthreads();

    // E) distance from register-held x; no second global read of x
    if (act) {
        float a0 = 0.f, a1 = 0.f, a2 = 0.f, a3 = 0.f;
#pragma unroll
        for (int dd = 0; dd < kDC; ++dd) {
            const float* m = &means_s[dd][0];
            const float d0 = va[dd].x - m[c0.x];
            const float d1 = va[dd].y - m[c0.y];
            const float d2 = va[dd].z - m[c0.z];
            const float d3 = va[dd].w - m[c0.w];
            a0 += d0 * d0; a1 += d1 * d1; a2 += d2 * d2; a3 += d3 * d3;
        }
        const float inv = 1.0f / (float)kD;
        float* ob = out + (size_t)b * kN + 4 * (size_t)tid;
        fadd_glb(ob + 0, a0 * inv);
        fadd_glb(ob + 1, a1 * inv);
        fadd_glb(ob + 2, a2 * inv);
        fadd_glb(ob + 3, a3 * inv);
    }
}

// ---------------------------------------------------------------------------
// DIAGNOSTIC: pure stream with identical geometry/access pattern, no LDS /
// atomics. Separate rocprof row => measures achievable BW for this pattern.
// Result stored to ws (coalesced) so nothing is DCE'd.
// ---------------------------------------------------------------------------
__global__ __launch_bounds__(kT) void k_stream(const float* __restrict__ x,
                                               float* __restrict__ ws)
{
    const int tid = threadIdx.x;
    if (tid >= kN4) return;
    const int chunk = blockIdx.x;
    const int b     = blockIdx.y;
    const float4* xp = (const float4*)(x + ((size_t)b * kD + (size_t)chunk * kDC) * kN);
    float a = 0.f;
#pragma unroll
    for (int dd = 0; dd < kDC; ++dd) {
        const float4 v = xp[(size_t)dd * kN4 + tid];
        a += v.x + v.y + v.z + v.w;
    }
    ws[((size_t)b * kNCH + chunk) * kN4 + tid] = a;   // 5.3 MB, coalesced
}

extern "C" void kernel_launch(void* const* d_in, const int* in_sizes, int n_in,
                              void* d_out, int out_size, void* d_ws, size_t ws_size,
                              hipStream_t stream) {
    const float* x   = (const float*)d_in[0];
    const int*   cm  = (const int*)d_in[1];
    float*       out = (float*)d_out;
    float*       ws  = (float*)d_ws;

    // Output re-poisoned to 0xAA before every timed launch; kernel accumulates.
    hipMemsetAsync(d_out, 0, (size_t)out_size * sizeof(float), stream);

    dim3 grid(kNCH, kB);   // 16 x 256 = 4096 blocks
    k_fused<<<grid, kT, 0, stream>>>(x, cm, out);
    // Diagnostic second so k_fused's counters stay comparable to prior rounds
    // (k_stream reads x L3-warm; its BW is an upper-bound probe).
    k_stream<<<grid, kT, 0, stream>>>(x, ws);
}

// Round 14
// 242.338 us; speedup vs baseline: 1.6669x; 1.1434x over previous
//
#include <hip/hip_runtime.h>

// Problem constants (match reference)
static constexpr int kB   = 256;      // batch
static constexpr int kD   = 128;      // proj dim
static constexpr int kN   = 1296;     // 36*36 pixels
static constexpr int kN4  = 324;      // float4 groups per row
static constexpr int kC   = 64;       // classes
static constexpr int kDC  = 8;        // d-rows per block -> x held in registers
static constexpr int kNCH = kD / kDC; // 16 chunks
static constexpr int kREP = 4;        // LDS sum replicas (quarter-wave keyed)
static constexpr int kT   = 384;      // 6 waves; lanes >= 324 idle in compute
static constexpr float kEPS = 1e-4f;
// Fixed-point scale for LDS int accumulation: 2^17.
// Worst case |sum| <= 1296 * 5sigma * 2^17 ~ 8.5e8 < 2^31. Quantization
// ~4e-6/element, negligible vs tolerance (absmax passed at 0.0078 twice).
static constexpr float kSCALE     = 131072.0f;
static constexpr float kINV_SCALE = 1.0f / 131072.0f;

// NOTE (round-13 lesson): fp32 atomicAdd lowered to a CAS retry loop killed
// rounds 3/9 (230us, VALU 2%). This version has ZERO fp atomics anywhere:
// LDS sums are int fixed-point (ds_add_u32), output is partial-store+reduce.

// ---------------------------------------------------------------------------
// k_fused: one block per (d-chunk, image). Thread t < 324 owns ONE float4
// pixel-group of each of the 8 d-rows. All 9 global loads (cm + 8 x-rows)
// are issued up front; LDS zeroing + barrier hide under their latency.
//   C) scatter to int fixed-point LDS sums (replica slots rotated by 8*rep)
//   D) merge replicas (unrotate), divide by count+eps -> float means
//   E) distance from REGISTER-held x; coalesced float4 partial store.
// ---------------------------------------------------------------------------
__global__ __launch_bounds__(kT) void k_fused(const float* __restrict__ x,
                                              const int*   __restrict__ cm,
                                              float* __restrict__ part)  // [NCH][B][N]
{
    __shared__ int   isum_s[kREP][kDC][kC];   // 8 KB fixed-point sums
    __shared__ float means_s[kDC][kC];        // 2 KB
    __shared__ int   cnt_s[kC];

    const int chunk = blockIdx.x;
    const int b     = blockIdx.y;
    const int tid   = threadIdx.x;
    const int rep   = (tid >> 4) & (kREP - 1);   // quarter-wave keyed
    const int rot   = rep << 3;                  // slot+bank decorrelation
    const bool act  = tid < kN4;

    // Issue ALL global loads first (latency overlaps LDS zero + barrier)
    int4 c0 = make_int4(0, 0, 0, 0);
    if (act) c0 = ((const int4*)(cm + (size_t)b * kN))[tid];

    const float4* xp = (const float4*)(x + ((size_t)b * kD + (size_t)chunk * kDC) * kN);
    float4 va[kDC];
#pragma unroll
    for (int dd = 0; dd < kDC; ++dd)
        va[dd] = act ? xp[(size_t)dd * kN4 + tid] : make_float4(0.f, 0.f, 0.f, 0.f);

    // Zero LDS while loads are in flight
    int4* z = (int4*)&isum_s[0][0][0];
    for (int i = tid; i < (kREP * kDC * kC) / 4; i += kT) z[i] = make_int4(0, 0, 0, 0);
    if (tid < kC) cnt_s[tid] = 0;
    __syncthreads();

    // C) counts + fixed-point scatter (all native int LDS atomics)
    if (act) {
        atomicAdd(&cnt_s[c0.x], 1);
        atomicAdd(&cnt_s[c0.y], 1);
        atomicAdd(&cnt_s[c0.z], 1);
        atomicAdd(&cnt_s[c0.w], 1);
        const int sx = (c0.x + rot) & (kC - 1);
        const int sy = (c0.y + rot) & (kC - 1);
        const int sz = (c0.z + rot) & (kC - 1);
        const int sw = (c0.w + rot) & (kC - 1);
#pragma unroll
        for (int dd = 0; dd < kDC; ++dd) {
            int* s = &isum_s[rep][dd][0];
            atomicAdd(s + sx, __float2int_rn(va[dd].x * kSCALE));
            atomicAdd(s + sy, __float2int_rn(va[dd].y * kSCALE));
            atomicAdd(s + sz, __float2int_rn(va[dd].z * kSCALE));
            atomicAdd(s + sw, __float2int_rn(va[dd].w * kSCALE));
        }
    }
    __syncthreads();

    // D) merge replicas (undo rotation) -> float means
    for (int i = tid; i < kDC * kC; i += kT) {
        const int dd = i >> 6;
        const int c  = i & (kC - 1);
        int s = isum_s[0][dd][c];                    // rot 0 = identity
#pragma unroll
        for (int r = 1; r < kREP; ++r)
            s += isum_s[r][dd][(c + (r << 3)) & (kC - 1)];
        means_s[dd][c] = (float)s * kINV_SCALE / ((float)cnt_s[c] + kEPS);
    }
    __syncthreads();

    // E) distance from register-held x; plain coalesced partial store
    if (act) {
        float a0 = 0.f, a1 = 0.f, a2 = 0.f, a3 = 0.f;
#pragma unroll
        for (int dd = 0; dd < kDC; ++dd) {
            const float* m = &means_s[dd][0];
            const float d0 = va[dd].x - m[c0.x];
            const float d1 = va[dd].y - m[c0.y];
            const float d2 = va[dd].z - m[c0.z];
            const float d3 = va[dd].w - m[c0.w];
            a0 += d0 * d0; a1 += d1 * d1; a2 += d2 * d2; a3 += d3 * d3;
        }
        float4 o; o.x = a0; o.y = a1; o.z = a2; o.w = a3;
        float* pb = part + ((size_t)chunk * kB + b) * kN;
        ((float4*)pb)[tid] = o;
    }
}

// ---------------------------------------------------------------------------
// k_reduce: out[b][n] = (1/D) * sum_chunk part[chunk][b][n]. Contention-free,
// fully coalesced; also the only writer of out (no memset needed).
// ---------------------------------------------------------------------------
__global__ __launch_bounds__(256) void k_reduce(const float* __restrict__ part,
                                                float* __restrict__ out)
{
    const size_t n4_total = (size_t)kB * kN / 4;               // 82944
    const size_t i = (size_t)blockIdx.x * 256 + threadIdx.x;   // float4 index
    if (i >= n4_total) return;

    float4 a = ((const float4*)part)[i];
#pragma unroll
    for (int c = 1; c < kNCH; ++c) {
        const float4 p = ((const float4*)part)[(size_t)c * n4_total + i];
        a.x += p.x; a.y += p.y; a.z += p.z; a.w += p.w;
    }
    const float inv = 1.0f / (float)kD;
    a.x *= inv; a.y *= inv; a.z *= inv; a.w *= inv;
    ((float4*)out)[i] = a;
}

extern "C" void kernel_launch(void* const* d_in, const int* in_sizes, int n_in,
                              void* d_out, int out_size, void* d_ws, size_t ws_size,
                              hipStream_t stream) {
    const float* x    = (const float*)d_in[0];
    const int*   cm   = (const int*)d_in[1];
    float*       out  = (float*)d_out;
    float*       part = (float*)d_ws;    // kNCH*kB*kN floats = 21.2 MB

    dim3 grid(kNCH, kB);   // 16 x 256 = 4096 blocks
    k_fused<<<grid, kT, 0, stream>>>(x, cm, part);

    const int n4_total = kB * kN / 4;    // 82944
    k_reduce<<<(n4_total + 255) / 256, 256, 0, stream>>>(part, out);
}